// Round 11
// baseline (608.963 us; speedup 1.0000x reference)
//
#include <hip/hip_runtime.h>

typedef unsigned int u32;
typedef unsigned long long u64;

#define Bn 16
#define Nn 1024
#define Pp 72
#define MARG 3e-4f

#define NEGINF __int_as_float(0xff800000)
#define POSINF __int_as_float(0x7f800000)

// ---------- DPP wave-64 reductions (VALU-only) ----------
#define DPP_STEP(OP, CTRL, RM)                                                 \
  y = __builtin_amdgcn_update_dpp(__float_as_int(v), __float_as_int(v),        \
                                  CTRL, RM, 0xf, false);                       \
  v = OP(v, __int_as_float(y));

#define DPP_RED(NAME, OP)                                                      \
  __device__ __forceinline__ float NAME(float v) {                             \
    int y;                                                                     \
    DPP_STEP(OP, 0x111, 0xf)                                                   \
    DPP_STEP(OP, 0x112, 0xf)                                                   \
    DPP_STEP(OP, 0x114, 0xf)                                                   \
    DPP_STEP(OP, 0x118, 0xf)                                                   \
    DPP_STEP(OP, 0x142, 0xa)                                                   \
    DPP_STEP(OP, 0x143, 0xc)                                                   \
    return __int_as_float(__builtin_amdgcn_readlane(__float_as_int(v), 63));   \
  }

#define FADDOP(a, b) ((a) + (b))
DPP_RED(dmaxf, fmaxf)
DPP_RED(dminf, fminf)
DPP_RED(dsumf, FADDOP)

__device__ __forceinline__ u32 wminu(u32 v) {
#pragma unroll
  for (int off = 1; off < 64; off <<= 1) {
    u32 o = (u32)__shfl_xor((int)v, off, 64);
    v = (o < v) ? o : v;
  }
  return v;
}

// ---------- shared selection: top-16 of q[16]-per-lane, renormalized ----------
// returns kept mask; fills v (sparse values). rescore via fp64 (rare).
template <int MODE>
__device__ __forceinline__ u32 select_row(const float* __restrict__ q,
                                          float* __restrict__ v, int l,
                                          const float* __restrict__ e1row,
                                          const double* __restrict__ edrow,
                                          const float* __restrict__ e2t,
                                          double Td) {
  float lm = q[0];
#pragma unroll
  for (int j = 1; j < 16; ++j) lm = fmaxf(lm, q[j]);
  const float qmax = dmaxf(lm);

  // bit-bisection for the 16th largest (q >= 0 -> float bits uint-ordered)
  u32 lo = 0u, hi = __float_as_uint(qmax) + 1u;
  u32 kept = 0u;
  bool f16 = false;
  float pvf = 0.0f;
#pragma unroll 1
  while (hi - lo > 1u) {
    u32 mid = (lo + hi) >> 1;
    float pv = __uint_as_float(mid);
    u32 cw = 0;
#pragma unroll
    for (int j = 0; j < 16; ++j)
      cw += (u32)__popcll(__ballot(q[j] >= pv));
    if (cw >= 16u) lo = mid; else hi = mid;
    if (cw == 16u) { f16 = true; pvf = pv; break; }
  }
  float theta, ub;
  if (f16) {
    float vmin = POSINF, umax = -1.0f;
#pragma unroll
    for (int j = 0; j < 16; ++j) {
      if (q[j] >= pvf) { kept |= 1u << j; vmin = fminf(vmin, q[j]); }
      else umax = fmaxf(umax, q[j]);
    }
    theta = dminf(vmin);   // 16th value
    ub = dmaxf(umax);      // 17th value
  } else {
    theta = __uint_as_float(lo);
    u32 cw = 0;
#pragma unroll
    for (int j = 0; j < 16; ++j) {
      cw += (u32)__popcll(__ballot(q[j] > theta));
      if (q[j] > theta) kept |= 1u << j;
    }
    int rr = 16 - (int)cw;
#pragma unroll 1
    for (int it = 0; it < rr; ++it) {
      u32 mc = 0xFFFFFFFFu;
#pragma unroll
      for (int j = 0; j < 16; ++j)
        if (q[j] == theta && !((kept >> j) & 1u)) {
          u32 cc = (u32)((j << 6) | l);
          mc = cc < mc ? cc : mc;
        }
      u32 wm = wminu(mc);
      if ((wm & 63u) == (u32)l) kept |= 1u << (wm >> 6);
    }
    ub = theta;  // gap 0 -> rescore
  }

  if (theta - ub >= MARG) {
    float e[16];
    float es = 0.0f, ek = 0.0f;
#pragma unroll
    for (int j = 0; j < 16; ++j) {
      e[j] = __expf(q[j] - qmax);
      es += e[j];
      if ((kept >> j) & 1u) ek += e[j];
    }
    const float Z = dsumf(es);
    const float EK = dsumf(ek);
    const float inv = 1.0f / (EK + 1e-8f * Z);
#pragma unroll
    for (int j = 0; j < 16; ++j)
      v[j] = ((kept >> j) & 1u) ? (e[j] * inv) : 0.0f;
    return kept;
  } else {
    // rescore path (rare): fp64 for boundary-adjacent cols
    double qd[16];
    const float thr = ub - MARG;
#pragma unroll 1
    for (int j = 0; j < 16; ++j) {
      if (q[j] >= thr) {
        const int m = l + (j << 6);
        const float* col = e2t + (size_t)m * 64;
        double a = 0.0;
        for (int d = 0; d < 64; ++d) {
          double s = (MODE == 0) ? (double)e1row[d] : edrow[d];
          a = fma(s, (double)col[d], a);
        }
        qd[j] = (a > 0.0 ? a : 0.0) / Td;
      } else {
        qd[j] = (double)q[j];
      }
    }
    double bm = qd[0];
#pragma unroll
    for (int j = 1; j < 16; ++j) bm = qd[j] > bm ? qd[j] : bm;
    float mh = (float)bm;
    float mlo = (float)(bm - (double)mh);
    float whi = dmaxf(mh);
    float wlo = dmaxf(mh == whi ? mlo : NEGINF);
    const double qmaxd = (double)whi + (double)wlo;

    float ev2[16];
    float es2 = 0.0f;
#pragma unroll
    for (int j = 0; j < 16; ++j) { ev2[j] = __expf((float)(qd[j] - qmaxd)); es2 += ev2[j]; }
    const float Z2 = dsumf(es2);

    u32 kept2 = 0;
    float EK2 = 0.0f;
#pragma unroll 1
    for (int it = 0; it < 16; ++it) {
      double bv = -1.0;
      int bjj = -1;
#pragma unroll
      for (int j = 0; j < 16; ++j) {
        bool tk = (((kept2 >> j) & 1u) == 0u) && (qd[j] > bv);
        bv = tk ? qd[j] : bv;
        bjj = tk ? j : bjj;
      }
      float bh = NEGINF, bl = NEGINF;
      if (bjj >= 0) { bh = (float)bv; bl = (float)(bv - (double)bh); }
      float vhi = dmaxf(bh);
      float vlo = dmaxf(bh == vhi ? bl : NEGINF);
      bool elig = (bh == vhi) && (bl == vlo);
      u32 mc = elig ? (u32)((bjj << 6) | l) : 0xFFFFFFFFu;
      u32 mwin = wminu(mc);
      EK2 += __expf((float)(((double)vhi + (double)vlo) - qmaxd));
      if ((mwin & 63u) == (u32)l) kept2 |= 1u << (mwin >> 6);
    }
    const float inv2 = 1.0f / (EK2 + 1e-8f * Z2);
#pragma unroll
    for (int j = 0; j < 16; ++j)
      v[j] = ((kept2 >> j) & 1u) ? (ev2[j] * inv2) : 0.0f;
    return kept2;
  }
}

// ---------- compact emission: 16 (val,col) pairs per row ----------
__device__ __forceinline__ void emit_compact(u32 kept, const float* __restrict__ v,
                                             int l, float* __restrict__ cbase) {
  const u64 lt = ((u64)1 << l) - 1;
  u32 cum = 0;
#pragma unroll
  for (int j = 0; j < 16; ++j) {
    u64 m = __ballot((kept >> j) & 1u);
    u32 idx = cum + (u32)__popcll(m & lt);
    if ((kept >> j) & 1u) {
      cbase[idx] = v[j];
      cbase[16 + idx] = __uint_as_float((u32)(l + (j << 6)));
    }
    cum += (u32)__popcll(m);
  }
}

// ---------- kernel 0: E2 transpose (per head): E2T[h][m][d] = E2[h][d][m] ----------
__global__ __launch_bounds__(256) void k_e2t(const float* __restrict__ E2,
                                             float* __restrict__ E2T) {
  __shared__ float tile[32][65];
  const int h = blockIdx.x >> 5;
  const int m0 = (blockIdx.x & 31) << 5;
  const float* src = E2 + (size_t)h * 65536;
  float* dst = E2T + (size_t)h * 65536;
  const int t = threadIdx.x;
#pragma unroll
  for (int k = 0; k < 8; ++k) {
    int idx = k * 256 + t;
    int d = idx >> 5, mm = idx & 31;
    tile[mm][d] = src[d * 1024 + m0 + mm];
  }
  __syncthreads();
#pragma unroll
  for (int k = 0; k < 8; ++k) {
    int idx = k * 256 + t;
    int mm = idx >> 6, d = idx & 63;
    dst[(size_t)(m0 + mm) * 64 + d] = tile[mm][d];
  }
}

// ---------- kernel 1: fused mean-over-P + node MLP (fp64), emits fp64+fp32 ----------
__global__ __launch_bounds__(128) void k_meanmlp(const float* __restrict__ pf,
                                                 const float* __restrict__ dW1,
                                                 const float* __restrict__ db1,
                                                 const float* __restrict__ ln_g,
                                                 const float* __restrict__ ln_b,
                                                 const float* __restrict__ dW2,
                                                 const float* __restrict__ db2,
                                                 double* __restrict__ embD,
                                                 float* __restrict__ embF) {
  __shared__ double ndD[96];
  __shared__ double red[64];
  __shared__ double h1r[64];
  const int t = threadIdx.x;
  const int bn = blockIdx.x;

  if (t < 96) {
    const float* src = pf + (size_t)bn * (Pp * 96) + t;
    double s = 0.0;
    for (int p = 0; p < Pp; ++p) s += (double)src[p * 96];
    ndD[t] = s / 72.0;
  }
  __syncthreads();

  double a = 0.0;
  if (t < 64) {
    a = (double)db1[t];
    for (int d = 0; d < 96; ++d) a = fma(ndD[d], (double)dW1[d * 64 + t], a);
    red[t] = a;
  }
  __syncthreads();
  for (int s2 = 32; s2 >= 1; s2 >>= 1) {
    if (t < s2) red[t] += red[t + s2];
    __syncthreads();
  }
  const double mu = red[0] * (1.0 / 64.0);
  __syncthreads();
  const double dv = a - mu;
  if (t < 64) red[t] = dv * dv;
  __syncthreads();
  for (int s2 = 32; s2 >= 1; s2 >>= 1) {
    if (t < s2) red[t] += red[t + s2];
    __syncthreads();
  }
  const double var = red[0] * (1.0 / 64.0);
  if (t < 64) {
    double xn = dv / sqrt(var + 1e-5) * (double)ln_g[t] + (double)ln_b[t];
    h1r[t] = xn > 0.0 ? xn : 0.0;
  }
  __syncthreads();
  if (t < 64) {
    double e = (double)db2[t];
    for (int k = 0; k < 64; ++k) e = fma(h1r[k], (double)dW2[k * 64 + t], e);
    embD[(size_t)bn * 64 + t] = e;
    embF[(size_t)bn * 64 + t] = (float)e;
  }
}

// ---------- kernel 2: DOT + SELECT fused — 8 rows/block ----------
// dense sparse rows to outp; compact (val,col) pairs to cmp. Logits never hit HBM.
// per-column fp32 fma order (d ascending) identical to prior rounds -> bit-identical.
template <int MODE>
__global__ __launch_bounds__(256) void k_dotsel(const float* __restrict__ e1f,
                                                const float* __restrict__ embF,
                                                const double* __restrict__ embD,
                                                const float* __restrict__ E2,
                                                const float* __restrict__ E2T,
                                                const float* __restrict__ temp,
                                                float* __restrict__ outp,
                                                float* __restrict__ cmp) {
  __shared__ float embsh[64][8];
  __shared__ float lgs[4][1024];
  const int t = threadIdx.x;
  const int r0 = blockIdx.x * 8;   // 8 rows per block, same head
  int h;
  size_t erow;
  if (MODE == 0) {
    h = r0 >> 10;
    erow = (size_t)r0;
  } else {
    int b = r0 >> 12;
    h = (r0 >> 10) & 3;
    int n0 = r0 & 1023;
    erow = (size_t)(b << 10) + n0;
  }
  const float* efa = (MODE == 0) ? (e1f + erow * 64) : (embF + erow * 64);
  const float* e2 = E2 + (size_t)h * 65536;
  const float* e2t = E2T + (size_t)h * 65536;
  const float invT = 1.0f / temp[h];
  const double Td = (double)temp[h];

  // stage emb fp32 into LDS (transposed [d][g]); 512 elems by 256 threads
  for (int i = t; i < 512; i += 256) {
    int g = i & 7, d = i >> 3;
    embsh[d][g] = efa[g * 64 + d];
  }
  __syncthreads();

  const int s = t >> 7;          // row subgroup: rows 4s .. 4s+3
  const int c1 = (t & 127) * 4;  // first col quad
  const int c2 = c1 + 512;       // second col quad

  float acc[4][8];
#pragma unroll
  for (int g = 0; g < 4; ++g)
#pragma unroll
    for (int x = 0; x < 8; ++x) acc[g][x] = 0.0f;

#pragma unroll 4
  for (int d = 0; d < 64; ++d) {
    float4 va = *(const float4*)(e2 + d * 1024 + c1);
    float4 vb = *(const float4*)(e2 + d * 1024 + c2);
    float4 ea = *(const float4*)&embsh[d][4 * s];
    float sg;
#define ROWFMA(g, SS)                                                          \
    sg = SS;                                                                   \
    acc[g][0] = fmaf(sg, va.x, acc[g][0]);                                     \
    acc[g][1] = fmaf(sg, va.y, acc[g][1]);                                     \
    acc[g][2] = fmaf(sg, va.z, acc[g][2]);                                     \
    acc[g][3] = fmaf(sg, va.w, acc[g][3]);                                     \
    acc[g][4] = fmaf(sg, vb.x, acc[g][4]);                                     \
    acc[g][5] = fmaf(sg, vb.y, acc[g][5]);                                     \
    acc[g][6] = fmaf(sg, vb.z, acc[g][6]);                                     \
    acc[g][7] = fmaf(sg, vb.w, acc[g][7]);
    ROWFMA(0, ea.x) ROWFMA(1, ea.y) ROWFMA(2, ea.z) ROWFMA(3, ea.w)
#undef ROWFMA
  }
  // relu * invT in place (same op/order as prior rounds)
#pragma unroll
  for (int g = 0; g < 4; ++g)
#pragma unroll
    for (int x = 0; x < 8; ++x) acc[g][x] = fmaxf(acc[g][x], 0.0f) * invT;

  const int w = t >> 6, l = t & 63;

  // two groups of 4 rows: stage to LDS -> one row per wave -> select -> write
#pragma unroll
  for (int gr = 0; gr < 2; ++gr) {
    if (s == gr) {
#pragma unroll
      for (int k = 0; k < 4; ++k) {
        float4 o1, o2;
        o1.x = acc[k][0]; o1.y = acc[k][1]; o1.z = acc[k][2]; o1.w = acc[k][3];
        o2.x = acc[k][4]; o2.y = acc[k][5]; o2.z = acc[k][6]; o2.w = acc[k][7];
        *(float4*)&lgs[k][c1] = o1;
        *(float4*)&lgs[k][c2] = o2;
      }
    }
    __syncthreads();
    {
      const int rloc = gr * 4 + w;
      const size_t r = (size_t)r0 + rloc;
      float q[16], v[16];
#pragma unroll
      for (int j = 0; j < 16; ++j) q[j] = lgs[w][l + (j << 6)];
      u32 kept = select_row<MODE>(
          q, v, l, (MODE == 0) ? (e1f + r * 64) : nullptr,
          (MODE == 1) ? (embD + (erow + rloc) * 64) : nullptr, e2t, Td);
      float* row = outp + r * 1024;
#pragma unroll
      for (int j = 0; j < 16; ++j) row[l + (j << 6)] = v[j];
      emit_compact(kept, v, l, cmp + r * 32);
    }
    __syncthreads();
  }
}

// ---------- kernel 3: fuse from compacts + edge MLP + head mean + final ----------
__global__ __launch_bounds__(256) void k_fusec(const float* __restrict__ cmpd,
                                               const float* __restrict__ cmp0,
                                               float* __restrict__ fin,
                                               const float* __restrict__ eW1,
                                               const float* __restrict__ eb1,
                                               const float* __restrict__ eW2,
                                               const float* __restrict__ eb2,
                                               const float* __restrict__ fwp) {
  __shared__ float fused[4][1024];
  const int t = threadIdx.x;
  const int bn = blockIdx.x;
  const int b = bn >> 10, n = bn & 1023;
  const float fw = fwp[0];
  const float w1 = 1.0f - fw;

  // zero the fused tile
  float4* fz = (float4*)&fused[0][0];
  float4 z; z.x = 0.f; z.y = 0.f; z.z = 0.f; z.w = 0.f;
#pragma unroll
  for (int k = 0; k < 4; ++k) fz[t + 256 * k] = z;
  __syncthreads();

  // scatter static pairs (race-free: distinct (h,col) per thread)
  if (t < 64) {
    int h = t >> 4, k = t & 15;
    const float* cb = cmp0 + ((size_t)(h * 1024 + n)) * 32;
    float val = cb[k];
    int col = (int)__float_as_uint(cb[16 + k]);
    fused[h][col] = w1 * val;
  }
  __syncthreads();
  // accumulate dynamic pairs
  if (t < 64) {
    int h = t >> 4, k = t & 15;
    const float* cb = cmpd + ((size_t)((b * 4 + h) * 1024 + n)) * 32;
    float val = cb[k];
    int col = (int)__float_as_uint(cb[16 + k]);
    fused[h][col] += fw * val;
  }
  __syncthreads();

  float W1[4][8], B1v[8], W2v[8];
#pragma unroll
  for (int hh = 0; hh < 4; ++hh)
#pragma unroll
    for (int j = 0; j < 8; ++j) W1[hh][j] = eW1[hh * 8 + j];
#pragma unroll
  for (int j = 0; j < 8; ++j) { B1v[j] = eb1[j]; W2v[j] = eW2[j]; }
  const float b2 = eb2[0];

  float* orow = fin + (size_t)bn * 1024;
#pragma unroll
  for (int k = 0; k < 4; ++k) {
    const int col = t + 256 * k;
    const float f0 = fused[0][col];
    const float f1 = fused[1][col];
    const float f2 = fused[2][col];
    const float f3 = fused[3][col];
    float ew = b2;
#pragma unroll
    for (int j = 0; j < 8; ++j) {
      float hj = B1v[j];
      hj = fmaf(f0, W1[0][j], hj);
      hj = fmaf(f1, W1[1][j], hj);
      hj = fmaf(f2, W1[2][j], hj);
      hj = fmaf(f3, W1[3][j], hj);
      ew = fmaf(fmaxf(hj, 0.0f), W2v[j], ew);
    }
    const float mean = (f0 + f1 + f2 + f3) * 0.25f;
    const float sg = 1.0f / (1.0f + __expf(-ew));
    orow[col] = sg * mean;   // all-zero cols: mean==0 -> exact 0
  }
}

// ---------- launch ----------
extern "C" void kernel_launch(void* const* d_in, const int* in_sizes, int n_in,
                              void* d_out, int out_size, void* d_ws, size_t ws_size,
                              hipStream_t stream) {
  const float* pf   = (const float*)d_in[0];
  const float* E1   = (const float*)d_in[1];
  const float* E2   = (const float*)d_in[2];
  const float* temp = (const float*)d_in[3];
  const float* fw   = (const float*)d_in[4];
  const float* dW1  = (const float*)d_in[5];
  const float* db1  = (const float*)d_in[6];
  const float* ln_g = (const float*)d_in[7];
  const float* ln_b = (const float*)d_in[8];
  const float* dW2  = (const float*)d_in[9];
  const float* db2  = (const float*)d_in[10];
  const float* eW1  = (const float*)d_in[11];
  const float* eb1  = (const float*)d_in[12];
  const float* eW2  = (const float*)d_in[13];
  const float* eb2  = (const float*)d_in[14];

  // outputs are fp32, concatenated flat
  float* out_final = (float*)d_out;                              // 16,777,216 f
  float* out_stat  = out_final + (size_t)Bn * Nn * Nn;           // + 4,194,304 f
  float* out_dyn   = out_stat + (size_t)4 * Nn * Nn;             // +67,108,864 f

  // scratch in d_ws (~1.8 GB available; we use ~22 MB)
  char* wsb = (char*)d_ws;
  double* embD = (double*)wsb;                                   // 8 MB
  float* embF  = (float*)(wsb + (8u << 20));                     // 4 MB
  float* E2T   = (float*)(wsb + (12u << 20));                    // 1 MB
  float* cmp0  = (float*)(wsb + (13u << 20));                    // 0.5 MB (4096*32 f)
  float* cmpd  = (float*)(wsb + (14u << 20));                    // 8 MB (65536*32 f)

  k_e2t<<<128, 256, 0, stream>>>(E2, E2T);
  k_meanmlp<<<Bn * Nn, 128, 0, stream>>>(pf, dW1, db1, ln_g, ln_b, dW2, db2, embD, embF);
  k_dotsel<0><<<512, 256, 0, stream>>>(E1, nullptr, nullptr, E2, E2T, temp, out_stat, cmp0);
  k_dotsel<1><<<8192, 256, 0, stream>>>(nullptr, embF, embD, E2, E2T, temp, out_dyn, cmpd);
  k_fusec<<<16384, 256, 0, stream>>>(cmpd, cmp0, out_final, eW1, eb1, eW2, eb2, fw);
}

// Round 12
// 574.369 us; speedup vs baseline: 1.0602x; 1.0602x over previous
//
#include <hip/hip_runtime.h>

typedef unsigned int u32;
typedef unsigned long long u64;

#define Bn 16
#define Nn 1024
#define Pp 72
#define MARG 3e-4f

#define NEGINF __int_as_float(0xff800000)
#define POSINF __int_as_float(0x7f800000)

// ---------- DPP wave-64 reductions (VALU-only) ----------
#define DPP_STEP(OP, CTRL, RM)                                                 \
  y = __builtin_amdgcn_update_dpp(__float_as_int(v), __float_as_int(v),        \
                                  CTRL, RM, 0xf, false);                       \
  v = OP(v, __int_as_float(y));

#define DPP_RED(NAME, OP)                                                      \
  __device__ __forceinline__ float NAME(float v) {                             \
    int y;                                                                     \
    DPP_STEP(OP, 0x111, 0xf)                                                   \
    DPP_STEP(OP, 0x112, 0xf)                                                   \
    DPP_STEP(OP, 0x114, 0xf)                                                   \
    DPP_STEP(OP, 0x118, 0xf)                                                   \
    DPP_STEP(OP, 0x142, 0xa)                                                   \
    DPP_STEP(OP, 0x143, 0xc)                                                   \
    return __int_as_float(__builtin_amdgcn_readlane(__float_as_int(v), 63));   \
  }

#define FADDOP(a, b) ((a) + (b))
DPP_RED(dmaxf, fmaxf)
DPP_RED(dminf, fminf)
DPP_RED(dsumf, FADDOP)

__device__ __forceinline__ u32 wminu(u32 v) {
#pragma unroll
  for (int off = 1; off < 64; off <<= 1) {
    u32 o = (u32)__shfl_xor((int)v, off, 64);
    v = (o < v) ? o : v;
  }
  return v;
}

// ---------- shared selection: top-16 of q[16]-per-lane, renormalized ----------
// returns kept mask; fills v (sparse values). rescore via fp64 (rare).
template <int MODE>
__device__ __forceinline__ u32 select_row(const float* __restrict__ q,
                                          float* __restrict__ v, int l,
                                          const float* __restrict__ e1row,
                                          const double* __restrict__ edrow,
                                          const float* __restrict__ e2t,
                                          double Td) {
  float lm = q[0];
#pragma unroll
  for (int j = 1; j < 16; ++j) lm = fmaxf(lm, q[j]);
  const float qmax = dmaxf(lm);

  // bit-bisection for the 16th largest (q >= 0 -> float bits uint-ordered)
  u32 lo = 0u, hi = __float_as_uint(qmax) + 1u;
  u32 kept = 0u;
  bool f16 = false;
  float pvf = 0.0f;
#pragma unroll 1
  while (hi - lo > 1u) {
    u32 mid = (lo + hi) >> 1;
    float pv = __uint_as_float(mid);
    u32 cw = 0;
#pragma unroll
    for (int j = 0; j < 16; ++j)
      cw += (u32)__popcll(__ballot(q[j] >= pv));
    if (cw >= 16u) lo = mid; else hi = mid;
    if (cw == 16u) { f16 = true; pvf = pv; break; }
  }
  float theta, ub;
  if (f16) {
    float vmin = POSINF, umax = -1.0f;
#pragma unroll
    for (int j = 0; j < 16; ++j) {
      if (q[j] >= pvf) { kept |= 1u << j; vmin = fminf(vmin, q[j]); }
      else umax = fmaxf(umax, q[j]);
    }
    theta = dminf(vmin);   // 16th value
    ub = dmaxf(umax);      // 17th value
  } else {
    theta = __uint_as_float(lo);
    u32 cw = 0;
#pragma unroll
    for (int j = 0; j < 16; ++j) {
      cw += (u32)__popcll(__ballot(q[j] > theta));
      if (q[j] > theta) kept |= 1u << j;
    }
    int rr = 16 - (int)cw;
#pragma unroll 1
    for (int it = 0; it < rr; ++it) {
      u32 mc = 0xFFFFFFFFu;
#pragma unroll
      for (int j = 0; j < 16; ++j)
        if (q[j] == theta && !((kept >> j) & 1u)) {
          u32 cc = (u32)((j << 6) | l);
          mc = cc < mc ? cc : mc;
        }
      u32 wm = wminu(mc);
      if ((wm & 63u) == (u32)l) kept |= 1u << (wm >> 6);
    }
    ub = theta;  // gap 0 -> rescore
  }

  if (theta - ub >= MARG) {
    float e[16];
    float es = 0.0f, ek = 0.0f;
#pragma unroll
    for (int j = 0; j < 16; ++j) {
      e[j] = __expf(q[j] - qmax);
      es += e[j];
      if ((kept >> j) & 1u) ek += e[j];
    }
    const float Z = dsumf(es);
    const float EK = dsumf(ek);
    const float inv = 1.0f / (EK + 1e-8f * Z);
#pragma unroll
    for (int j = 0; j < 16; ++j)
      v[j] = ((kept >> j) & 1u) ? (e[j] * inv) : 0.0f;
    return kept;
  } else {
    // rescore path (rare): fp64 for boundary-adjacent cols
    double qd[16];
    const float thr = ub - MARG;
#pragma unroll 1
    for (int j = 0; j < 16; ++j) {
      if (q[j] >= thr) {
        const int m = l + (j << 6);
        const float* col = e2t + (size_t)m * 64;
        double a = 0.0;
        for (int d = 0; d < 64; ++d) {
          double s = (MODE == 0) ? (double)e1row[d] : edrow[d];
          a = fma(s, (double)col[d], a);
        }
        qd[j] = (a > 0.0 ? a : 0.0) / Td;
      } else {
        qd[j] = (double)q[j];
      }
    }
    double bm = qd[0];
#pragma unroll
    for (int j = 1; j < 16; ++j) bm = qd[j] > bm ? qd[j] : bm;
    float mh = (float)bm;
    float mlo = (float)(bm - (double)mh);
    float whi = dmaxf(mh);
    float wlo = dmaxf(mh == whi ? mlo : NEGINF);
    const double qmaxd = (double)whi + (double)wlo;

    float ev2[16];
    float es2 = 0.0f;
#pragma unroll
    for (int j = 0; j < 16; ++j) { ev2[j] = __expf((float)(qd[j] - qmaxd)); es2 += ev2[j]; }
    const float Z2 = dsumf(es2);

    u32 kept2 = 0;
    float EK2 = 0.0f;
#pragma unroll 1
    for (int it = 0; it < 16; ++it) {
      double bv = -1.0;
      int bjj = -1;
#pragma unroll
      for (int j = 0; j < 16; ++j) {
        bool tk = (((kept2 >> j) & 1u) == 0u) && (qd[j] > bv);
        bv = tk ? qd[j] : bv;
        bjj = tk ? j : bjj;
      }
      float bh = NEGINF, bl = NEGINF;
      if (bjj >= 0) { bh = (float)bv; bl = (float)(bv - (double)bh); }
      float vhi = dmaxf(bh);
      float vlo = dmaxf(bh == vhi ? bl : NEGINF);
      bool elig = (bh == vhi) && (bl == vlo);
      u32 mc = elig ? (u32)((bjj << 6) | l) : 0xFFFFFFFFu;
      u32 mwin = wminu(mc);
      EK2 += __expf((float)(((double)vhi + (double)vlo) - qmaxd));
      if ((mwin & 63u) == (u32)l) kept2 |= 1u << (mwin >> 6);
    }
    const float inv2 = 1.0f / (EK2 + 1e-8f * Z2);
#pragma unroll
    for (int j = 0; j < 16; ++j)
      v[j] = ((kept2 >> j) & 1u) ? (ev2[j] * inv2) : 0.0f;
    return kept2;
  }
}

// ---------- compact emission: 16 (val,col) pairs per row ----------
__device__ __forceinline__ void emit_compact(u32 kept, const float* __restrict__ v,
                                             int l, float* __restrict__ cbase) {
  const u64 lt = ((u64)1 << l) - 1;
  u32 cum = 0;
#pragma unroll
  for (int j = 0; j < 16; ++j) {
    u64 m = __ballot((kept >> j) & 1u);
    u32 idx = cum + (u32)__popcll(m & lt);
    if ((kept >> j) & 1u) {
      cbase[idx] = v[j];
      cbase[16 + idx] = __uint_as_float((u32)(l + (j << 6)));
    }
    cum += (u32)__popcll(m);
  }
}

// ---------- kernel 0: E2 transpose (per head): E2T[h][m][d] = E2[h][d][m] ----------
__global__ __launch_bounds__(256) void k_e2t(const float* __restrict__ E2,
                                             float* __restrict__ E2T) {
  __shared__ float tile[32][65];
  const int h = blockIdx.x >> 5;
  const int m0 = (blockIdx.x & 31) << 5;
  const float* src = E2 + (size_t)h * 65536;
  float* dst = E2T + (size_t)h * 65536;
  const int t = threadIdx.x;
#pragma unroll
  for (int k = 0; k < 8; ++k) {
    int idx = k * 256 + t;
    int d = idx >> 5, mm = idx & 31;
    tile[mm][d] = src[d * 1024 + m0 + mm];
  }
  __syncthreads();
#pragma unroll
  for (int k = 0; k < 8; ++k) {
    int idx = k * 256 + t;
    int mm = idx >> 6, d = idx & 63;
    dst[(size_t)(m0 + mm) * 64 + d] = tile[mm][d];
  }
}

// ---------- kernel 1: fused mean-over-P + node MLP (fp64), emits fp64+fp32 ----------
__global__ __launch_bounds__(128) void k_meanmlp(const float* __restrict__ pf,
                                                 const float* __restrict__ dW1,
                                                 const float* __restrict__ db1,
                                                 const float* __restrict__ ln_g,
                                                 const float* __restrict__ ln_b,
                                                 const float* __restrict__ dW2,
                                                 const float* __restrict__ db2,
                                                 double* __restrict__ embD,
                                                 float* __restrict__ embF) {
  __shared__ double ndD[96];
  __shared__ double red[64];
  __shared__ double h1r[64];
  const int t = threadIdx.x;
  const int bn = blockIdx.x;

  if (t < 96) {
    const float* src = pf + (size_t)bn * (Pp * 96) + t;
    double s = 0.0;
    for (int p = 0; p < Pp; ++p) s += (double)src[p * 96];
    ndD[t] = s / 72.0;
  }
  __syncthreads();

  double a = 0.0;
  if (t < 64) {
    a = (double)db1[t];
    for (int d = 0; d < 96; ++d) a = fma(ndD[d], (double)dW1[d * 64 + t], a);
    red[t] = a;
  }
  __syncthreads();
  for (int s2 = 32; s2 >= 1; s2 >>= 1) {
    if (t < s2) red[t] += red[t + s2];
    __syncthreads();
  }
  const double mu = red[0] * (1.0 / 64.0);
  __syncthreads();
  const double dv = a - mu;
  if (t < 64) red[t] = dv * dv;
  __syncthreads();
  for (int s2 = 32; s2 >= 1; s2 >>= 1) {
    if (t < s2) red[t] += red[t + s2];
    __syncthreads();
  }
  const double var = red[0] * (1.0 / 64.0);
  if (t < 64) {
    double xn = dv / sqrt(var + 1e-5) * (double)ln_g[t] + (double)ln_b[t];
    h1r[t] = xn > 0.0 ? xn : 0.0;
  }
  __syncthreads();
  if (t < 64) {
    double e = (double)db2[t];
    for (int k = 0; k < 64; ++k) e = fma(h1r[k], (double)dW2[k * 64 + t], e);
    embD[(size_t)bn * 64 + t] = e;
    embF[(size_t)bn * 64 + t] = (float)e;
  }
}

// ---------- kernel 2: DOT — 16 rows/block, 8 cols/thread, logits to global ----------
// per-column fp32 fma order (d ascending) identical to prior rounds -> bit-identical.
template <int MODE>
__global__ __launch_bounds__(256) void k_dot(const float* __restrict__ e1f,
                                             const float* __restrict__ embF,
                                             const float* __restrict__ E2,
                                             const float* __restrict__ temp,
                                             float* __restrict__ outp) {
  __shared__ float embsh[64][16];
  const int t = threadIdx.x;
  const int r0 = blockIdx.x * 16;   // 16 rows per block, same head
  int h;
  size_t erow;
  if (MODE == 0) {
    h = r0 >> 10;
    erow = (size_t)r0;
  } else {
    int b = r0 >> 12;
    h = (r0 >> 10) & 3;
    int n0 = r0 & 1023;
    erow = (size_t)(b << 10) + n0;
  }
  const float* efa = (MODE == 0) ? (e1f + erow * 64) : (embF + erow * 64);
  const float* e2 = E2 + (size_t)h * 65536;
  const float invT = 1.0f / temp[h];

  // stage emb fp32 into LDS (transposed [d][g]); 1024 elems by 256 threads
#pragma unroll
  for (int i = t; i < 1024; i += 256) {
    int g = i & 15, d = i >> 4;
    embsh[d][g] = efa[g * 64 + d];
  }
  __syncthreads();

  const int s = t >> 7;          // row subgroup: rows 8s .. 8s+7
  const int c1 = (t & 127) * 4;  // first col quad
  const int c2 = c1 + 512;       // second col quad

  float acc[8][8];
#pragma unroll
  for (int g = 0; g < 8; ++g)
#pragma unroll
    for (int x = 0; x < 8; ++x) acc[g][x] = 0.0f;

#pragma unroll 4
  for (int d = 0; d < 64; ++d) {
    float4 va = *(const float4*)(e2 + d * 1024 + c1);
    float4 vb = *(const float4*)(e2 + d * 1024 + c2);
    float4 ea = *(const float4*)&embsh[d][8 * s];
    float4 eb = *(const float4*)&embsh[d][8 * s + 4];
    float sg;
#define ROWFMA(g, SS)                                                          \
    sg = SS;                                                                   \
    acc[g][0] = fmaf(sg, va.x, acc[g][0]);                                     \
    acc[g][1] = fmaf(sg, va.y, acc[g][1]);                                     \
    acc[g][2] = fmaf(sg, va.z, acc[g][2]);                                     \
    acc[g][3] = fmaf(sg, va.w, acc[g][3]);                                     \
    acc[g][4] = fmaf(sg, vb.x, acc[g][4]);                                     \
    acc[g][5] = fmaf(sg, vb.y, acc[g][5]);                                     \
    acc[g][6] = fmaf(sg, vb.z, acc[g][6]);                                     \
    acc[g][7] = fmaf(sg, vb.w, acc[g][7]);
    ROWFMA(0, ea.x) ROWFMA(1, ea.y) ROWFMA(2, ea.z) ROWFMA(3, ea.w)
    ROWFMA(4, eb.x) ROWFMA(5, eb.y) ROWFMA(6, eb.z) ROWFMA(7, eb.w)
#undef ROWFMA
  }

#pragma unroll
  for (int g = 0; g < 8; ++g) {
    float* orow = outp + (size_t)(r0 + 8 * s + g) * 1024;
    float4 o1, o2;
    o1.x = fmaxf(acc[g][0], 0.0f) * invT;
    o1.y = fmaxf(acc[g][1], 0.0f) * invT;
    o1.z = fmaxf(acc[g][2], 0.0f) * invT;
    o1.w = fmaxf(acc[g][3], 0.0f) * invT;
    o2.x = fmaxf(acc[g][4], 0.0f) * invT;
    o2.y = fmaxf(acc[g][5], 0.0f) * invT;
    o2.z = fmaxf(acc[g][6], 0.0f) * invT;
    o2.w = fmaxf(acc[g][7], 0.0f) * invT;
    *(float4*)(orow + c1) = o1;
    *(float4*)(orow + c2) = o2;
  }
}

// ---------- kernel 3: SELECT — 1 row/wave, in-place sparsify + compact ----------
template <int MODE>
__global__ __launch_bounds__(256) void k_selc(const float* __restrict__ e1f,
                                              const double* __restrict__ embD,
                                              const float* __restrict__ E2T,
                                              const float* __restrict__ temp,
                                              float* __restrict__ outp,
                                              float* __restrict__ cmp) {
  const int t = threadIdx.x;
  const int w = t >> 6, l = t & 63;
  const int r = blockIdx.x * 4 + w;   // absolute row
  int h;
  size_t erow;
  if (MODE == 0) {
    h = r >> 10;
    erow = (size_t)r;
  } else {
    int b = r >> 12;
    h = (r >> 10) & 3;
    int n = r & 1023;
    erow = (size_t)(b << 10) + n;
  }
  const float* e2t = E2T + (size_t)h * 65536;
  const double Td = (double)temp[h];
  float* row = outp + (size_t)r * 1024;

  float q[16], v[16];
#pragma unroll
  for (int j = 0; j < 16; ++j) q[j] = row[l + (j << 6)];

  u32 kept = select_row<MODE>(q, v, l,
                              (MODE == 0) ? (e1f + erow * 64) : nullptr,
                              (MODE == 1) ? (embD + erow * 64) : nullptr,
                              e2t, Td);
#pragma unroll
  for (int j = 0; j < 16; ++j) row[l + (j << 6)] = v[j];
  emit_compact(kept, v, l, cmp + (size_t)r * 32);
}

// ---------- kernel 4: fuse from compacts + edge MLP + head mean + final ----------
__global__ __launch_bounds__(256) void k_fusec(const float* __restrict__ cmpd,
                                               const float* __restrict__ cmp0,
                                               float* __restrict__ fin,
                                               const float* __restrict__ eW1,
                                               const float* __restrict__ eb1,
                                               const float* __restrict__ eW2,
                                               const float* __restrict__ eb2,
                                               const float* __restrict__ fwp) {
  __shared__ float fused[4][1024];
  const int t = threadIdx.x;
  const int bn = blockIdx.x;
  const int b = bn >> 10, n = bn & 1023;
  const float fw = fwp[0];
  const float w1 = 1.0f - fw;

  // zero the fused tile
  float4* fz = (float4*)&fused[0][0];
  float4 z; z.x = 0.f; z.y = 0.f; z.z = 0.f; z.w = 0.f;
#pragma unroll
  for (int k = 0; k < 4; ++k) fz[t + 256 * k] = z;
  __syncthreads();

  // scatter static pairs (race-free: distinct (h,col) per thread)
  if (t < 64) {
    int h = t >> 4, k = t & 15;
    const float* cb = cmp0 + ((size_t)(h * 1024 + n)) * 32;
    float val = cb[k];
    int col = (int)__float_as_uint(cb[16 + k]);
    fused[h][col] = w1 * val;
  }
  __syncthreads();
  // accumulate dynamic pairs
  if (t < 64) {
    int h = t >> 4, k = t & 15;
    const float* cb = cmpd + ((size_t)((b * 4 + h) * 1024 + n)) * 32;
    float val = cb[k];
    int col = (int)__float_as_uint(cb[16 + k]);
    fused[h][col] += fw * val;
  }
  __syncthreads();

  float W1[4][8], B1v[8], W2v[8];
#pragma unroll
  for (int hh = 0; hh < 4; ++hh)
#pragma unroll
    for (int j = 0; j < 8; ++j) W1[hh][j] = eW1[hh * 8 + j];
#pragma unroll
  for (int j = 0; j < 8; ++j) { B1v[j] = eb1[j]; W2v[j] = eW2[j]; }
  const float b2 = eb2[0];

  float* orow = fin + (size_t)bn * 1024;
#pragma unroll
  for (int k = 0; k < 4; ++k) {
    const int col = t + 256 * k;
    const float f0 = fused[0][col];
    const float f1 = fused[1][col];
    const float f2 = fused[2][col];
    const float f3 = fused[3][col];
    float ew = b2;
#pragma unroll
    for (int j = 0; j < 8; ++j) {
      float hj = B1v[j];
      hj = fmaf(f0, W1[0][j], hj);
      hj = fmaf(f1, W1[1][j], hj);
      hj = fmaf(f2, W1[2][j], hj);
      hj = fmaf(f3, W1[3][j], hj);
      ew = fmaf(fmaxf(hj, 0.0f), W2v[j], ew);
    }
    const float mean = (f0 + f1 + f2 + f3) * 0.25f;
    const float sg = 1.0f / (1.0f + __expf(-ew));
    orow[col] = sg * mean;   // all-zero cols: mean==0 -> exact 0
  }
}

// ---------- launch ----------
extern "C" void kernel_launch(void* const* d_in, const int* in_sizes, int n_in,
                              void* d_out, int out_size, void* d_ws, size_t ws_size,
                              hipStream_t stream) {
  const float* pf   = (const float*)d_in[0];
  const float* E1   = (const float*)d_in[1];
  const float* E2   = (const float*)d_in[2];
  const float* temp = (const float*)d_in[3];
  const float* fw   = (const float*)d_in[4];
  const float* dW1  = (const float*)d_in[5];
  const float* db1  = (const float*)d_in[6];
  const float* ln_g = (const float*)d_in[7];
  const float* ln_b = (const float*)d_in[8];
  const float* dW2  = (const float*)d_in[9];
  const float* db2  = (const float*)d_in[10];
  const float* eW1  = (const float*)d_in[11];
  const float* eb1  = (const float*)d_in[12];
  const float* eW2  = (const float*)d_in[13];
  const float* eb2  = (const float*)d_in[14];

  // outputs are fp32, concatenated flat
  float* out_final = (float*)d_out;                              // 16,777,216 f
  float* out_stat  = out_final + (size_t)Bn * Nn * Nn;           // + 4,194,304 f
  float* out_dyn   = out_stat + (size_t)4 * Nn * Nn;             // +67,108,864 f

  // scratch in d_ws (~1.8 GB available; we use ~22 MB)
  char* wsb = (char*)d_ws;
  double* embD = (double*)wsb;                                   // 8 MB
  float* embF  = (float*)(wsb + (8u << 20));                     // 4 MB
  float* E2T   = (float*)(wsb + (12u << 20));                    // 1 MB
  float* cmp0  = (float*)(wsb + (13u << 20));                    // 0.5 MB (4096*32 f)
  float* cmpd  = (float*)(wsb + (14u << 20));                    // 8 MB (65536*32 f)

  k_e2t<<<128, 256, 0, stream>>>(E2, E2T);
  k_meanmlp<<<Bn * Nn, 128, 0, stream>>>(pf, dW1, db1, ln_g, ln_b, dW2, db2, embD, embF);
  k_dot<0><<<256, 256, 0, stream>>>(E1, nullptr, E2, temp, out_stat);
  k_selc<0><<<1024, 256, 0, stream>>>(E1, nullptr, E2T, temp, out_stat, cmp0);
  k_dot<1><<<4096, 256, 0, stream>>>(nullptr, embF, E2, temp, out_dyn);
  k_selc<1><<<16384, 256, 0, stream>>>(nullptr, embD, E2T, temp, out_dyn, cmpd);
  k_fusec<<<16384, 256, 0, stream>>>(cmpd, cmp0, out_final, eW1, eb1, eW2, eb2, fw);
}

// Round 13
// 568.826 us; speedup vs baseline: 1.0706x; 1.0097x over previous
//
#include <hip/hip_runtime.h>

typedef unsigned int u32;
typedef unsigned long long u64;

#define Bn 16
#define Nn 1024
#define Pp 72
#define MARG 3e-4f

#define NEGINF __int_as_float(0xff800000)
#define POSINF __int_as_float(0x7f800000)

// ---------- DPP wave-64 reductions (VALU-only) ----------
#define DPP_STEP(OP, CTRL, RM)                                                 \
  y = __builtin_amdgcn_update_dpp(__float_as_int(v), __float_as_int(v),        \
                                  CTRL, RM, 0xf, false);                       \
  v = OP(v, __int_as_float(y));

#define DPP_RED(NAME, OP)                                                      \
  __device__ __forceinline__ float NAME(float v) {                             \
    int y;                                                                     \
    DPP_STEP(OP, 0x111, 0xf)                                                   \
    DPP_STEP(OP, 0x112, 0xf)                                                   \
    DPP_STEP(OP, 0x114, 0xf)                                                   \
    DPP_STEP(OP, 0x118, 0xf)                                                   \
    DPP_STEP(OP, 0x142, 0xa)                                                   \
    DPP_STEP(OP, 0x143, 0xc)                                                   \
    return __int_as_float(__builtin_amdgcn_readlane(__float_as_int(v), 63));   \
  }

#define FADDOP(a, b) ((a) + (b))
DPP_RED(dmaxf, fmaxf)
DPP_RED(dminf, fminf)
DPP_RED(dsumf, FADDOP)

__device__ __forceinline__ u32 wminu(u32 v) {
#pragma unroll
  for (int off = 1; off < 64; off <<= 1) {
    u32 o = (u32)__shfl_xor((int)v, off, 64);
    v = (o < v) ? o : v;
  }
  return v;
}

// ---------- shared selection: top-16 of q[16]-per-lane, renormalized ----------
template <int MODE>
__device__ __forceinline__ void select_row(const float* __restrict__ q,
                                           float* __restrict__ v, int l,
                                           const float* __restrict__ e1row,
                                           const double* __restrict__ edrow,
                                           const float* __restrict__ e2t,
                                           double Td) {
  float lm = q[0];
#pragma unroll
  for (int j = 1; j < 16; ++j) lm = fmaxf(lm, q[j]);
  const float qmax = dmaxf(lm);

  // bit-bisection for the 16th largest (q >= 0 -> float bits uint-ordered)
  u32 lo = 0u, hi = __float_as_uint(qmax) + 1u;
  u32 kept = 0u;
  bool f16 = false;
  float pvf = 0.0f;
#pragma unroll 1
  while (hi - lo > 1u) {
    u32 mid = (lo + hi) >> 1;
    float pv = __uint_as_float(mid);
    u32 cw = 0;
#pragma unroll
    for (int j = 0; j < 16; ++j)
      cw += (u32)__popcll(__ballot(q[j] >= pv));
    if (cw >= 16u) lo = mid; else hi = mid;
    if (cw == 16u) { f16 = true; pvf = pv; break; }
  }
  float theta, ub;
  if (f16) {
    float vmin = POSINF, umax = -1.0f;
#pragma unroll
    for (int j = 0; j < 16; ++j) {
      if (q[j] >= pvf) { kept |= 1u << j; vmin = fminf(vmin, q[j]); }
      else umax = fmaxf(umax, q[j]);
    }
    theta = dminf(vmin);   // 16th value
    ub = dmaxf(umax);      // 17th value
  } else {
    theta = __uint_as_float(lo);
    u32 cw = 0;
#pragma unroll
    for (int j = 0; j < 16; ++j) {
      cw += (u32)__popcll(__ballot(q[j] > theta));
      if (q[j] > theta) kept |= 1u << j;
    }
    int rr = 16 - (int)cw;
#pragma unroll 1
    for (int it = 0; it < rr; ++it) {
      u32 mc = 0xFFFFFFFFu;
#pragma unroll
      for (int j = 0; j < 16; ++j)
        if (q[j] == theta && !((kept >> j) & 1u)) {
          u32 cc = (u32)((j << 6) | l);
          mc = cc < mc ? cc : mc;
        }
      u32 wm = wminu(mc);
      if ((wm & 63u) == (u32)l) kept |= 1u << (wm >> 6);
    }
    ub = theta;  // gap 0 -> rescore
  }

  if (theta - ub >= MARG) {
    float e[16];
    float es = 0.0f, ek = 0.0f;
#pragma unroll
    for (int j = 0; j < 16; ++j) {
      e[j] = __expf(q[j] - qmax);
      es += e[j];
      if ((kept >> j) & 1u) ek += e[j];
    }
    const float Z = dsumf(es);
    const float EK = dsumf(ek);
    const float inv = 1.0f / (EK + 1e-8f * Z);
#pragma unroll
    for (int j = 0; j < 16; ++j)
      v[j] = ((kept >> j) & 1u) ? (e[j] * inv) : 0.0f;
  } else {
    // rescore path (rare): fp64 for boundary-adjacent cols
    double qd[16];
    const float thr = ub - MARG;
#pragma unroll 1
    for (int j = 0; j < 16; ++j) {
      if (q[j] >= thr) {
        const int m = l + (j << 6);
        const float* col = e2t + (size_t)m * 64;
        double a = 0.0;
        for (int d = 0; d < 64; ++d) {
          double s = (MODE == 0) ? (double)e1row[d] : edrow[d];
          a = fma(s, (double)col[d], a);
        }
        qd[j] = (a > 0.0 ? a : 0.0) / Td;
      } else {
        qd[j] = (double)q[j];
      }
    }
    double bm = qd[0];
#pragma unroll
    for (int j = 1; j < 16; ++j) bm = qd[j] > bm ? qd[j] : bm;
    float mh = (float)bm;
    float mlo = (float)(bm - (double)mh);
    float whi = dmaxf(mh);
    float wlo = dmaxf(mh == whi ? mlo : NEGINF);
    const double qmaxd = (double)whi + (double)wlo;

    float ev2[16];
    float es2 = 0.0f;
#pragma unroll
    for (int j = 0; j < 16; ++j) { ev2[j] = __expf((float)(qd[j] - qmaxd)); es2 += ev2[j]; }
    const float Z2 = dsumf(es2);

    u32 kept2 = 0;
    float EK2 = 0.0f;
#pragma unroll 1
    for (int it = 0; it < 16; ++it) {
      double bv = -1.0;
      int bjj = -1;
#pragma unroll
      for (int j = 0; j < 16; ++j) {
        bool tk = (((kept2 >> j) & 1u) == 0u) && (qd[j] > bv);
        bv = tk ? qd[j] : bv;
        bjj = tk ? j : bjj;
      }
      float bh = NEGINF, bl = NEGINF;
      if (bjj >= 0) { bh = (float)bv; bl = (float)(bv - (double)bh); }
      float vhi = dmaxf(bh);
      float vlo = dmaxf(bh == vhi ? bl : NEGINF);
      bool elig = (bh == vhi) && (bl == vlo);
      u32 mc = elig ? (u32)((bjj << 6) | l) : 0xFFFFFFFFu;
      u32 mwin = wminu(mc);
      EK2 += __expf((float)(((double)vhi + (double)vlo) - qmaxd));
      if ((mwin & 63u) == (u32)l) kept2 |= 1u << (mwin >> 6);
    }
    const float inv2 = 1.0f / (EK2 + 1e-8f * Z2);
#pragma unroll
    for (int j = 0; j < 16; ++j)
      v[j] = ((kept2 >> j) & 1u) ? (ev2[j] * inv2) : 0.0f;
  }
}

// ---------- kernel 0: E2 transpose (per head): E2T[h][m][d] = E2[h][d][m] ----------
__global__ __launch_bounds__(256) void k_e2t(const float* __restrict__ E2,
                                             float* __restrict__ E2T) {
  __shared__ float tile[32][65];
  const int h = blockIdx.x >> 5;
  const int m0 = (blockIdx.x & 31) << 5;
  const float* src = E2 + (size_t)h * 65536;
  float* dst = E2T + (size_t)h * 65536;
  const int t = threadIdx.x;
#pragma unroll
  for (int k = 0; k < 8; ++k) {
    int idx = k * 256 + t;
    int d = idx >> 5, mm = idx & 31;
    tile[mm][d] = src[d * 1024 + m0 + mm];
  }
  __syncthreads();
#pragma unroll
  for (int k = 0; k < 8; ++k) {
    int idx = k * 256 + t;
    int mm = idx >> 6, d = idx & 63;
    dst[(size_t)(m0 + mm) * 64 + d] = tile[mm][d];
  }
}

// ---------- kernel 1: fused mean-over-P + node MLP (fp64), emits fp64+fp32 ----------
__global__ __launch_bounds__(128) void k_meanmlp(const float* __restrict__ pf,
                                                 const float* __restrict__ dW1,
                                                 const float* __restrict__ db1,
                                                 const float* __restrict__ ln_g,
                                                 const float* __restrict__ ln_b,
                                                 const float* __restrict__ dW2,
                                                 const float* __restrict__ db2,
                                                 double* __restrict__ embD,
                                                 float* __restrict__ embF) {
  __shared__ double ndD[96];
  __shared__ double red[64];
  __shared__ double h1r[64];
  const int t = threadIdx.x;
  const int bn = blockIdx.x;

  if (t < 96) {
    const float* src = pf + (size_t)bn * (Pp * 96) + t;
    double s = 0.0;
    for (int p = 0; p < Pp; ++p) s += (double)src[p * 96];
    ndD[t] = s / 72.0;
  }
  __syncthreads();

  double a = 0.0;
  if (t < 64) {
    a = (double)db1[t];
    for (int d = 0; d < 96; ++d) a = fma(ndD[d], (double)dW1[d * 64 + t], a);
    red[t] = a;
  }
  __syncthreads();
  for (int s2 = 32; s2 >= 1; s2 >>= 1) {
    if (t < s2) red[t] += red[t + s2];
    __syncthreads();
  }
  const double mu = red[0] * (1.0 / 64.0);
  __syncthreads();
  const double dv = a - mu;
  if (t < 64) red[t] = dv * dv;
  __syncthreads();
  for (int s2 = 32; s2 >= 1; s2 >>= 1) {
    if (t < s2) red[t] += red[t + s2];
    __syncthreads();
  }
  const double var = red[0] * (1.0 / 64.0);
  if (t < 64) {
    double xn = dv / sqrt(var + 1e-5) * (double)ln_g[t] + (double)ln_b[t];
    h1r[t] = xn > 0.0 ? xn : 0.0;
  }
  __syncthreads();
  if (t < 64) {
    double e = (double)db2[t];
    for (int k = 0; k < 64; ++k) e = fma(h1r[k], (double)dW2[k * 64 + t], e);
    embD[(size_t)bn * 64 + t] = e;
    embF[(size_t)bn * 64 + t] = (float)e;
  }
}

// ---------- kernel 2: DOT — 16 rows/block, 8 cols/thread, logits to global ----------
// rbase: starting row of this launch chunk (rows in (b,h,n) flat order).
template <int MODE>
__global__ __launch_bounds__(256) void k_dot(const float* __restrict__ e1f,
                                             const float* __restrict__ embF,
                                             const float* __restrict__ E2,
                                             const float* __restrict__ temp,
                                             float* __restrict__ outp,
                                             int rbase) {
  __shared__ float embsh[64][16];
  const int t = threadIdx.x;
  const int r0 = rbase + blockIdx.x * 16;   // 16 rows per block, same head
  int h;
  size_t erow;
  if (MODE == 0) {
    h = r0 >> 10;
    erow = (size_t)r0;
  } else {
    int b = r0 >> 12;
    h = (r0 >> 10) & 3;
    int n0 = r0 & 1023;
    erow = (size_t)(b << 10) + n0;
  }
  const float* efa = (MODE == 0) ? (e1f + erow * 64) : (embF + erow * 64);
  const float* e2 = E2 + (size_t)h * 65536;
  const float invT = 1.0f / temp[h];

  // stage emb fp32 into LDS (transposed [d][g]); 1024 elems by 256 threads
#pragma unroll
  for (int i = t; i < 1024; i += 256) {
    int g = i & 15, d = i >> 4;
    embsh[d][g] = efa[g * 64 + d];
  }
  __syncthreads();

  const int s = t >> 7;          // row subgroup: rows 8s .. 8s+7
  const int c1 = (t & 127) * 4;  // first col quad
  const int c2 = c1 + 512;       // second col quad

  float acc[8][8];
#pragma unroll
  for (int g = 0; g < 8; ++g)
#pragma unroll
    for (int x = 0; x < 8; ++x) acc[g][x] = 0.0f;

#pragma unroll 4
  for (int d = 0; d < 64; ++d) {
    float4 va = *(const float4*)(e2 + d * 1024 + c1);
    float4 vb = *(const float4*)(e2 + d * 1024 + c2);
    float4 ea = *(const float4*)&embsh[d][8 * s];
    float4 eb = *(const float4*)&embsh[d][8 * s + 4];
    float sg;
#define ROWFMA(g, SS)                                                          \
    sg = SS;                                                                   \
    acc[g][0] = fmaf(sg, va.x, acc[g][0]);                                     \
    acc[g][1] = fmaf(sg, va.y, acc[g][1]);                                     \
    acc[g][2] = fmaf(sg, va.z, acc[g][2]);                                     \
    acc[g][3] = fmaf(sg, va.w, acc[g][3]);                                     \
    acc[g][4] = fmaf(sg, vb.x, acc[g][4]);                                     \
    acc[g][5] = fmaf(sg, vb.y, acc[g][5]);                                     \
    acc[g][6] = fmaf(sg, vb.z, acc[g][6]);                                     \
    acc[g][7] = fmaf(sg, vb.w, acc[g][7]);
    ROWFMA(0, ea.x) ROWFMA(1, ea.y) ROWFMA(2, ea.z) ROWFMA(3, ea.w)
    ROWFMA(4, eb.x) ROWFMA(5, eb.y) ROWFMA(6, eb.z) ROWFMA(7, eb.w)
#undef ROWFMA
  }

#pragma unroll
  for (int g = 0; g < 8; ++g) {
    float* orow = outp + (size_t)(r0 + 8 * s + g) * 1024;
    float4 o1, o2;
    o1.x = fmaxf(acc[g][0], 0.0f) * invT;
    o1.y = fmaxf(acc[g][1], 0.0f) * invT;
    o1.z = fmaxf(acc[g][2], 0.0f) * invT;
    o1.w = fmaxf(acc[g][3], 0.0f) * invT;
    o2.x = fmaxf(acc[g][4], 0.0f) * invT;
    o2.y = fmaxf(acc[g][5], 0.0f) * invT;
    o2.z = fmaxf(acc[g][6], 0.0f) * invT;
    o2.w = fmaxf(acc[g][7], 0.0f) * invT;
    *(float4*)(orow + c1) = o1;
    *(float4*)(orow + c2) = o2;
  }
}

// ---------- kernel 3: SELECT (static rows) — 1 row/wave, in-place ----------
__global__ __launch_bounds__(256) void k_sel0(const float* __restrict__ E1,
                                              const float* __restrict__ E2T,
                                              const float* __restrict__ temp,
                                              float* __restrict__ outp) {
  const int t = threadIdx.x;
  const int w = t >> 6, l = t & 63;
  const int r = blockIdx.x * 4 + w;
  const int h = r >> 10;
  const float* e2t = E2T + (size_t)h * 65536;
  const double Td = (double)temp[h];
  float* row = outp + (size_t)r * 1024;

  float q[16], v[16];
#pragma unroll
  for (int j = 0; j < 16; ++j) q[j] = row[l + (j << 6)];
  select_row<0>(q, v, l, E1 + (size_t)r * 64, nullptr, e2t, Td);
#pragma unroll
  for (int j = 0; j < 16; ++j) row[l + (j << 6)] = v[j];
}

// ---------- kernel 4: SELECT dyn + fuse + edge MLP + final (per (b,n)) ----------
// bnbase: starting (b*1024+n) index of this launch chunk.
__global__ __launch_bounds__(256) void k_selfuse(float* __restrict__ dyn,
                                                 const float* __restrict__ stat,
                                                 float* __restrict__ fin,
                                                 const double* __restrict__ embD,
                                                 const float* __restrict__ E2T,
                                                 const float* __restrict__ temp,
                                                 const float* __restrict__ eW1,
                                                 const float* __restrict__ eb1,
                                                 const float* __restrict__ eW2,
                                                 const float* __restrict__ eb2,
                                                 const float* __restrict__ fwp,
                                                 int bnbase) {
  __shared__ float rowbuf[4][1024];   // sparse dyn values, one row per head
  const int t = threadIdx.x;
  const int w = t >> 6, l = t & 63;   // wave w = head w
  const int bn = bnbase + blockIdx.x;
  const int b = bn >> 10, n = bn & 1023;

  // --- selection phase: wave w sparsifies dyn[b, w, n, :] ---
  {
    const int h = w;
    float* row = dyn + (((size_t)((b * 4 + h) * 1024 + n)) << 10);
    const float* e2t = E2T + (size_t)h * 65536;
    const double Td = (double)temp[h];
    float q[16], v[16];
#pragma unroll
    for (int j = 0; j < 16; ++j) q[j] = row[l + (j << 6)];
    select_row<1>(q, v, l, nullptr, embD + (((size_t)(b << 10) + n) << 6), e2t, Td);
#pragma unroll
    for (int j = 0; j < 16; ++j) rowbuf[h][l + (j << 6)] = v[j];
  }
  __syncthreads();

  // --- write sparse dyn rows (coalesced float4) ---
#pragma unroll
  for (int k = 0; k < 4; ++k) {
    int idx = t + 256 * k;            // 1024 float4 slots
    int h2 = idx >> 8, c4 = idx & 255;
    float* drow = dyn + (((size_t)((b * 4 + h2) * 1024 + n)) << 10);
    *(float4*)(drow + c4 * 4) = *(const float4*)&rowbuf[h2][c4 * 4];
  }

  // --- fuse + edge MLP + head-mean + sigmoid for final[b, n, :] ---
  const float fw = fwp[0];
  const float w1 = 1.0f - fw;
  float W1[4][8], B1v[8], W2v[8];
#pragma unroll
  for (int hh = 0; hh < 4; ++hh)
#pragma unroll
    for (int j = 0; j < 8; ++j) W1[hh][j] = eW1[hh * 8 + j];
#pragma unroll
  for (int j = 0; j < 8; ++j) { B1v[j] = eb1[j]; W2v[j] = eW2[j]; }
  const float b2 = eb2[0];

  float fx[4][4];
#pragma unroll
  for (int hh = 0; hh < 4; ++hh) {
    float4 fd = *(const float4*)&rowbuf[hh][t * 4];
    float4 fs = *(const float4*)(stat + (((size_t)(hh * 1024 + n)) << 10) + t * 4);
    fx[hh][0] = w1 * fs.x + fw * fd.x;
    fx[hh][1] = w1 * fs.y + fw * fd.y;
    fx[hh][2] = w1 * fs.z + fw * fd.z;
    fx[hh][3] = w1 * fs.w + fw * fd.w;
  }
  float ov[4];
#pragma unroll
  for (int x = 0; x < 4; ++x) {
    float ew = b2;
#pragma unroll
    for (int j = 0; j < 8; ++j) {
      float hj = B1v[j];
#pragma unroll
      for (int hh = 0; hh < 4; ++hh) hj = fmaf(fx[hh][x], W1[hh][j], hj);
      ew = fmaf(fmaxf(hj, 0.0f), W2v[j], ew);
    }
    float mean = (fx[0][x] + fx[1][x] + fx[2][x] + fx[3][x]) * 0.25f;
    float sg = 1.0f / (1.0f + __expf(-ew));
    ov[x] = sg * mean;
  }
  float4 o;
  o.x = ov[0]; o.y = ov[1]; o.z = ov[2]; o.w = ov[3];
  *(float4*)(fin + (size_t)b * 1048576 + (size_t)n * 1024 + t * 4) = o;
}

// ---------- launch ----------
extern "C" void kernel_launch(void* const* d_in, const int* in_sizes, int n_in,
                              void* d_out, int out_size, void* d_ws, size_t ws_size,
                              hipStream_t stream) {
  const float* pf   = (const float*)d_in[0];
  const float* E1   = (const float*)d_in[1];
  const float* E2   = (const float*)d_in[2];
  const float* temp = (const float*)d_in[3];
  const float* fw   = (const float*)d_in[4];
  const float* dW1  = (const float*)d_in[5];
  const float* db1  = (const float*)d_in[6];
  const float* ln_g = (const float*)d_in[7];
  const float* ln_b = (const float*)d_in[8];
  const float* dW2  = (const float*)d_in[9];
  const float* db2  = (const float*)d_in[10];
  const float* eW1  = (const float*)d_in[11];
  const float* eb1  = (const float*)d_in[12];
  const float* eW2  = (const float*)d_in[13];
  const float* eb2  = (const float*)d_in[14];

  // outputs are fp32, concatenated flat
  float* out_final = (float*)d_out;                              // 16,777,216 f
  float* out_stat  = out_final + (size_t)Bn * Nn * Nn;           // + 4,194,304 f
  float* out_dyn   = out_stat + (size_t)4 * Nn * Nn;             // +67,108,864 f

  // scratch in d_ws (~1.8 GB available; we use 13 MB)
  char* wsb = (char*)d_ws;
  double* embD = (double*)wsb;                                   // 8 MB
  float* embF  = (float*)(wsb + (8u << 20));                     // 4 MB
  float* E2T   = (float*)(wsb + (12u << 20));                    // 1 MB

  k_e2t<<<128, 256, 0, stream>>>(E2, E2T);
  k_meanmlp<<<Bn * Nn, 128, 0, stream>>>(pf, dW1, db1, ln_g, ln_b, dW2, db2, embD, embF);
  k_dot<0><<<256, 256, 0, stream>>>(E1, nullptr, E2, temp, out_stat, 0);
  k_sel0<<<1024, 256, 0, stream>>>(E1, E2T, temp, out_stat);

  // dyn path, chunked by batch so the dense-logit round-trip stays L3-resident:
  // 2 chunks x 8 batches = 134 MB logits per chunk << 256 MB Infinity Cache.
  for (int c = 0; c < 2; ++c) {
    const int rbase = c * 32768;     // 8 batches x 4 heads x 1024 rows
    const int bnbase = c * 8192;     // 8 batches x 1024 (b,n) pairs
    k_dot<1><<<2048, 256, 0, stream>>>(nullptr, embF, E2, temp, out_dyn, rbase);
    k_selfuse<<<8192, 256, 0, stream>>>(out_dyn, out_stat, out_final, embD, E2T,
                                        temp, eW1, eb1, eW2, eb2, fw, bnbase);
  }
}